// Round 3
// baseline (520.547 us; speedup 1.0000x reference)
//
#include <hip/hip_runtime.h>
#include <hip/hip_bf16.h>
#include <stdint.h>

#define TOKENS 8192
#define NOUT   4096
#define KIN    4096

#define BM 128
#define BN 128
#define BK 32

typedef __attribute__((ext_vector_type(8))) short bf16x8;
typedef __attribute__((ext_vector_type(4))) float f32x4;

__device__ __forceinline__ uint32_t rotl32(uint32_t x, int r) {
  return (x << r) | (x >> (32 - r));
}

// float -> bf16 round-to-nearest-even (no NaN handling needed here)
__device__ __forceinline__ uint16_t f2bf_rne(float f) {
  uint32_t u = __float_as_uint(f);
  u += 0x7FFFu + ((u >> 16) & 1u);
  return (uint16_t)(u >> 16);
}

// Threefry-2x32, 20 rounds — replica of JAX's PRNG core.
__device__ __forceinline__ void threefry2x32(uint32_t k0, uint32_t k1,
                                             uint32_t c0, uint32_t c1,
                                             uint32_t& o0, uint32_t& o1) {
  uint32_t ks2 = 0x1BD11BDAu ^ k0 ^ k1;
  uint32_t x0 = c0 + k0;
  uint32_t x1 = c1 + k1;
#define TFR(r) { x0 += x1; x1 = rotl32(x1, (r)); x1 ^= x0; }
  TFR(13) TFR(15) TFR(26) TFR(6)
  x0 += k1;  x1 += ks2 + 1u;
  TFR(17) TFR(29) TFR(16) TFR(24)
  x0 += ks2; x1 += k0 + 2u;
  TFR(13) TFR(15) TFR(26) TFR(6)
  x0 += k0;  x1 += k1 + 3u;
  TFR(17) TFR(29) TFR(16) TFR(24)
  x0 += k1;  x1 += ks2 + 4u;
  TFR(13) TFR(15) TFR(26) TFR(6)
  x0 += ks2; x1 += k0 + 5u;
#undef TFR
  o0 = x0; o1 = x1;
}

// Hydrate W[4096][4096] (row-major [out][in]) as bf16 from the seed.
// JAX >= 0.4.36 default: jax_threefry_partitionable=True. That path is:
//   counter = uint64 linear index j -> words (hi, lo) = (0, j)
//   (b1, b2) = threefry2x32(key=(0, seed), (0, j))
//   bits[j]  = b1 ^ b2                       (32-bit output width)
// float = bitcast((bits>>9)|0x3F800000) - 1; val = max(mn, f*(mx-mn)+mn)
__global__ void hydrate_w_kernel(uint16_t* __restrict__ W,
                                 const int* __restrict__ seed_ptr) {
  uint32_t k1 = (uint32_t)(*seed_ptr);            // key = (0, seed)
  uint32_t j = blockIdx.x * 256u + threadIdx.x;   // 0 .. 2^24-1
  uint32_t o0, o1;
  threefry2x32(0u, k1, 0u, j, o0, o1);
  uint32_t bits = o0 ^ o1;
  const float scale = 0.03125f;    // maxval - minval = 2/64
  const float mn    = -0.015625f;  // -1/sqrt(4096)
  float f = __uint_as_float((bits >> 9) | 0x3F800000u) - 1.0f;
  float v = fmaxf(mn, f * scale + mn);
  W[j] = f2bf_rne(v);
}

// C[M][N] = X[M][K] * W[N][K]^T + bias.
// Unchanged from round 2 (boring data path): reg-staged ds_write + syncthreads,
// single LDS buffer, in-register fp32->bf16 cvt for X.
__global__ __launch_bounds__(256)
void gemm_bias_kernel(const float* __restrict__ X,      // [TOKENS][KIN] fp32
                      const uint16_t* __restrict__ W,   // [NOUT][KIN] bf16
                      const float* __restrict__ bias,
                      float* __restrict__ C) {
  __shared__ uint16_t As[BM][BK];
  __shared__ uint16_t Bs[BN][BK];

  const int nwgn = NOUT / BN;                  // 32
  const int bid  = blockIdx.x;
  const int tm = (bid / nwgn) * BM;
  const int tn = (bid % nwgn) * BN;

  const int t    = threadIdx.x;
  const int lane = t & 63;
  const int wid  = t >> 6;
  const int wr   = (wid >> 1) * 64;            // wave row band
  const int wc   = (wid & 1) * 64;             // wave col band
  const int fr   = lane & 15;                  // frag row (A) / col (B)
  const int fq   = lane >> 4;                  // k-group 0..3

  f32x4 acc[4][4];
  const f32x4 zero = {0.f, 0.f, 0.f, 0.f};
#pragma unroll
  for (int i = 0; i < 4; ++i)
#pragma unroll
    for (int j = 0; j < 4; ++j) acc[i][j] = zero;

  // staging assignment: thread t owns row (t>>1), k-half (t&1)*16
  const int srow = t >> 1;                     // 0..127
  const int skq  = (t & 1) * 16;               // 0 or 16
  const float*    xrow = X + (size_t)(tm + srow) * KIN + skq;
  const uint16_t* wrow = W + (size_t)(tn + srow) * KIN + skq;

  for (int kt = 0; kt < KIN / BK; ++kt) {
    const int k0 = kt * BK;

    // global -> regs (A fp32 with in-register cvt, B bf16)
    f32x4 a0 = *(const f32x4*)(xrow + k0);
    f32x4 a1 = *(const f32x4*)(xrow + k0 + 4);
    f32x4 a2 = *(const f32x4*)(xrow + k0 + 8);
    f32x4 a3 = *(const f32x4*)(xrow + k0 + 12);
    bf16x8 b0 = *(const bf16x8*)(wrow + k0);
    bf16x8 b1 = *(const bf16x8*)(wrow + k0 + 8);

    union { uint16_t u[16]; bf16x8 v[2]; } ac;
#pragma unroll
    for (int j = 0; j < 4; ++j) {
      ac.u[j]      = f2bf_rne(a0[j]);
      ac.u[4 + j]  = f2bf_rne(a1[j]);
      ac.u[8 + j]  = f2bf_rne(a2[j]);
      ac.u[12 + j] = f2bf_rne(a3[j]);
    }

    __syncthreads();   // previous iteration's LDS reads complete
    *(bf16x8*)&As[srow][skq]     = ac.v[0];
    *(bf16x8*)&As[srow][skq + 8] = ac.v[1];
    *(bf16x8*)&Bs[srow][skq]     = b0;
    *(bf16x8*)&Bs[srow][skq + 8] = b1;
    __syncthreads();   // staging visible to all

    // LDS -> frags, 16 MFMA (verified m89/m91/m92 layouts)
    bf16x8 af[4], bfr[4];
#pragma unroll
    for (int mi = 0; mi < 4; ++mi)
      af[mi] = *(const bf16x8*)&As[wr + mi * 16 + fr][fq * 8];
#pragma unroll
    for (int ni = 0; ni < 4; ++ni)
      bfr[ni] = *(const bf16x8*)&Bs[wc + ni * 16 + fr][fq * 8];
#pragma unroll
    for (int mi = 0; mi < 4; ++mi)
#pragma unroll
      for (int ni = 0; ni < 4; ++ni)
        acc[mi][ni] = __builtin_amdgcn_mfma_f32_16x16x32_bf16(
            af[mi], bfr[ni], acc[mi][ni], 0, 0, 0);
  }

  // epilogue: D row = fq*4 + r, col = fr (m89/m91-verified), fused bias
#pragma unroll
  for (int ni = 0; ni < 4; ++ni) {
    const int col = tn + wc + ni * 16 + fr;
    const float bv = bias[col];
#pragma unroll
    for (int mi = 0; mi < 4; ++mi) {
      const int row0 = tm + wr + mi * 16 + fq * 4;
#pragma unroll
      for (int r = 0; r < 4; ++r)
        C[(size_t)(row0 + r) * NOUT + col] = acc[mi][ni][r] + bv;
    }
  }
}

extern "C" void kernel_launch(void* const* d_in, const int* in_sizes, int n_in,
                              void* d_out, int out_size, void* d_ws, size_t ws_size,
                              hipStream_t stream) {
  const float* x    = (const float*)d_in[0];   // [8192][4096] fp32
  const float* bias = (const float*)d_in[1];   // [4096] fp32
  const int*   seed = (const int*)d_in[2];     // [1] int
  float* y = (float*)d_out;                    // [8192][4096] fp32

  uint16_t* Wb = (uint16_t*)d_ws;              // 32 MB bf16 W

  // partitionable-threefry hydration: one element per thread, 2^24 total
  hydrate_w_kernel<<<(1u << 24) / 256, 256, 0, stream>>>(Wb, seed);

  const int grid = (TOKENS / BM) * (NOUT / BN);   // 2048
  gemm_bias_kernel<<<grid, 256, 0, stream>>>(x, Wb, bias, y);
}

// Round 4
// 395.502 us; speedup vs baseline: 1.3162x; 1.3162x over previous
//
#include <hip/hip_runtime.h>
#include <hip/hip_bf16.h>
#include <stdint.h>

#define TOKENS 8192
#define NOUT   4096
#define KIN    4096

#define BM 128
#define BN 128
#define BK 32

typedef __attribute__((ext_vector_type(8))) short bf16x8;
typedef __attribute__((ext_vector_type(4))) float f32x4;

__device__ __forceinline__ uint32_t rotl32(uint32_t x, int r) {
  return (x << r) | (x >> (32 - r));
}

// float -> bf16 round-to-nearest-even (no NaN handling needed here)
__device__ __forceinline__ uint16_t f2bf_rne(float f) {
  uint32_t u = __float_as_uint(f);
  u += 0x7FFFu + ((u >> 16) & 1u);
  return (uint16_t)(u >> 16);
}

// Threefry-2x32, 20 rounds — replica of JAX's PRNG core.
__device__ __forceinline__ void threefry2x32(uint32_t k0, uint32_t k1,
                                             uint32_t c0, uint32_t c1,
                                             uint32_t& o0, uint32_t& o1) {
  uint32_t ks2 = 0x1BD11BDAu ^ k0 ^ k1;
  uint32_t x0 = c0 + k0;
  uint32_t x1 = c1 + k1;
#define TFR(r) { x0 += x1; x1 = rotl32(x1, (r)); x1 ^= x0; }
  TFR(13) TFR(15) TFR(26) TFR(6)
  x0 += k1;  x1 += ks2 + 1u;
  TFR(17) TFR(29) TFR(16) TFR(24)
  x0 += ks2; x1 += k0 + 2u;
  TFR(13) TFR(15) TFR(26) TFR(6)
  x0 += k0;  x1 += k1 + 3u;
  TFR(17) TFR(29) TFR(16) TFR(24)
  x0 += k1;  x1 += ks2 + 4u;
  TFR(13) TFR(15) TFR(26) TFR(6)
  x0 += ks2; x1 += k0 + 5u;
#undef TFR
  o0 = x0; o1 = x1;
}

// Hydrate W[4096][4096] (row-major [out][in]) as bf16 from the seed.
// JAX (jax_threefry_partitionable=True, default >=0.4.36):
//   (b1, b2) = threefry2x32(key=(0, seed), counter=(0, j));  bits = b1 ^ b2
// float = bitcast((bits>>9)|0x3F800000) - 1; val = max(mn, f*(mx-mn)+mn)
// VERIFIED round 3: absmax 1.56e-2 (bf16-quant level).
__global__ void hydrate_w_kernel(uint16_t* __restrict__ W,
                                 const int* __restrict__ seed_ptr) {
  uint32_t k1 = (uint32_t)(*seed_ptr);            // key = (0, seed)
  uint32_t j = blockIdx.x * 256u + threadIdx.x;   // 0 .. 2^24-1
  uint32_t o0, o1;
  threefry2x32(0u, k1, 0u, j, o0, o1);
  uint32_t bits = o0 ^ o1;
  const float scale = 0.03125f;    // maxval - minval = 2/64
  const float mn    = -0.015625f;  // -1/sqrt(4096)
  float f = __uint_as_float((bits >> 9) | 0x3F800000u) - 1.0f;
  float v = fmaxf(mn, f * scale + mn);
  W[j] = f2bf_rne(v);
}

// x fp32 -> bf16, 8 elements/thread (removes per-k-step cvt from the GEMM)
__global__ void convert_x_kernel(const float* __restrict__ x,
                                 uint16_t* __restrict__ xb) {
  uint32_t base = (blockIdx.x * 256u + threadIdx.x) * 8u;
  f32x4 a = *(const f32x4*)(x + base);
  f32x4 b = *(const f32x4*)(x + base + 4);
  union { uint16_t u[8]; bf16x8 v; } r;
  r.u[0] = f2bf_rne(a[0]); r.u[1] = f2bf_rne(a[1]);
  r.u[2] = f2bf_rne(a[2]); r.u[3] = f2bf_rne(a[3]);
  r.u[4] = f2bf_rne(b[0]); r.u[5] = f2bf_rne(b[1]);
  r.u[6] = f2bf_rne(b[2]); r.u[7] = f2bf_rne(b[3]);
  *(bf16x8*)(xb + base) = r.v;
}

// C[M][N] = A[M][K] * B[N][K]^T + bias, bf16 in, fp32 out.
// m97 structure (measured 874-912 TF): 128x128 tile, BK=32, 4 waves,
// 4x4 16x16x32 frags/wave, global_load_lds(16B) staging, double-buffered
// LDS, 2-phase schedule, XCD-bijective swizzle.
// Correctness-verified in round 1 (bit-identical to the boring path).
__global__ __launch_bounds__(256, 2)
void gemm_bias_kernel(const uint16_t* __restrict__ A,   // x  bf16 [TOKENS][KIN]
                      const uint16_t* __restrict__ B,   // W  bf16 [NOUT][KIN]
                      const float* __restrict__ bias,
                      float* __restrict__ C) {
  __shared__ uint16_t As[2][BM][BK];
  __shared__ uint16_t Bs[2][BN][BK];

  const int nwgn = NOUT / BN;                 // 32
  const int nwg  = (TOKENS / BM) * nwgn;      // 2048 (divisible by 8)
  int bid = blockIdx.x;
  int cpx = nwg >> 3;
  int swz = (bid & 7) * cpx + (bid >> 3);     // bijective XCD swizzle
  int tm = (swz / nwgn) * BM;
  int tn = (swz % nwgn) * BN;

  const int t    = threadIdx.x;
  const int lane = t & 63;
  const int wid  = t >> 6;
  const int wr   = (wid >> 1) * 64;           // wave row band
  const int wc   = (wid & 1) * 64;            // wave col band
  const int fr   = lane & 15;                 // frag row (A) / col (B)
  const int fq   = lane >> 4;                 // k-group 0..3

  f32x4 acc[4][4];
  const f32x4 zero = {0.f, 0.f, 0.f, 0.f};
#pragma unroll
  for (int i = 0; i < 4; ++i)
#pragma unroll
    for (int j = 0; j < 4; ++j) acc[i][j] = zero;

  const int rsub = t >> 2;          // 0..63 : row within 64-row half-tile
  const int csub = (t & 3) * 8;     // 0,8,16,24 : k-offset (elements)
  // LDS dest = base + wave*1024B + lane*16B  -> contiguous in lane order,
  // satisfying global_load_lds's wave-uniform-base+lane*size requirement.

  auto stage = [&](int buf, int kt) {
    const int k0 = kt * BK;
#pragma unroll
    for (int i = 0; i < 2; ++i) {
      __builtin_amdgcn_global_load_lds(
          (const __attribute__((address_space(1))) void*)
              (A + (size_t)(tm + i * 64 + rsub) * KIN + k0 + csub),
          (__attribute__((address_space(3))) void*)(&As[buf][i * 64 + rsub][csub]),
          16, 0, 0);
      __builtin_amdgcn_global_load_lds(
          (const __attribute__((address_space(1))) void*)
              (B + (size_t)(tn + i * 64 + rsub) * KIN + k0 + csub),
          (__attribute__((address_space(3))) void*)(&Bs[buf][i * 64 + rsub][csub]),
          16, 0, 0);
    }
  };

  auto compute = [&](int buf) {
    bf16x8 af[4], bfr[4];
#pragma unroll
    for (int mi = 0; mi < 4; ++mi)
      af[mi] = *(const bf16x8*)&As[buf][wr + mi * 16 + fr][fq * 8];
#pragma unroll
    for (int ni = 0; ni < 4; ++ni)
      bfr[ni] = *(const bf16x8*)&Bs[buf][wc + ni * 16 + fr][fq * 8];
#pragma unroll
    for (int mi = 0; mi < 4; ++mi)
#pragma unroll
      for (int ni = 0; ni < 4; ++ni)
        acc[mi][ni] = __builtin_amdgcn_mfma_f32_16x16x32_bf16(
            af[mi], bfr[ni], acc[mi][ni], 0, 0, 0);
  };

  stage(0, 0);
  asm volatile("s_waitcnt vmcnt(0)" ::: "memory");
  __builtin_amdgcn_s_barrier();

  int cur = 0;
  for (int kt = 0; kt < KIN / BK - 1; ++kt) {
    stage(cur ^ 1, kt + 1);       // prefetch next tile into other buffer
    compute(cur);                 // MFMA on current tile
    asm volatile("s_waitcnt vmcnt(0)" ::: "memory");
    __builtin_amdgcn_s_barrier();
    cur ^= 1;
  }
  compute(cur);

  // epilogue: D row = fq*4 + r, col = fr (m89/m91-verified), fused bias
#pragma unroll
  for (int ni = 0; ni < 4; ++ni) {
    const int col = tn + wc + ni * 16 + fr;
    const float bv = bias[col];
#pragma unroll
    for (int mi = 0; mi < 4; ++mi) {
      const int row0 = tm + wr + mi * 16 + fq * 4;
#pragma unroll
      for (int r = 0; r < 4; ++r)
        C[(size_t)(row0 + r) * NOUT + col] = acc[mi][ni][r] + bv;
    }
  }
}

extern "C" void kernel_launch(void* const* d_in, const int* in_sizes, int n_in,
                              void* d_out, int out_size, void* d_ws, size_t ws_size,
                              hipStream_t stream) {
  const float* x    = (const float*)d_in[0];   // [8192][4096] fp32
  const float* bias = (const float*)d_in[1];   // [4096] fp32
  const int*   seed = (const int*)d_in[2];     // [1] int
  float* y = (float*)d_out;                    // [8192][4096] fp32

  // workspace: W bf16 (32 MB) | x bf16 (64 MB) — 96 MB, proven in round 1
  uint16_t* Wb = (uint16_t*)d_ws;
  uint16_t* Xb = Wb + (size_t)NOUT * KIN;

  hydrate_w_kernel<<<(1u << 24) / 256, 256, 0, stream>>>(Wb, seed);
  convert_x_kernel<<<(TOKENS * KIN / 8) / 256, 256, 0, stream>>>(x, Xb);

  const int grid = (TOKENS / BM) * (NOUT / BN);   // 2048
  gemm_bias_kernel<<<grid, 256, 0, stream>>>(Xb, Wb, bias, y);
}

// Round 5
// 315.295 us; speedup vs baseline: 1.6510x; 1.2544x over previous
//
#include <hip/hip_runtime.h>
#include <hip/hip_bf16.h>
#include <stdint.h>

#define TOKENS 8192
#define NOUT   4096
#define KIN    4096

#define BM 256
#define BN 256
#define BK 64
#define NT (KIN / BK)   // 64 K-tiles

typedef __attribute__((ext_vector_type(8))) short bf16x8;
typedef __attribute__((ext_vector_type(4))) float f32x4;

__device__ __forceinline__ uint32_t rotl32(uint32_t x, int r) {
  return (x << r) | (x >> (32 - r));
}

__device__ __forceinline__ uint16_t f2bf_rne(float f) {
  uint32_t u = __float_as_uint(f);
  u += 0x7FFFu + ((u >> 16) & 1u);
  return (uint16_t)(u >> 16);
}

// Threefry-2x32, 20 rounds — JAX PRNG core.
__device__ __forceinline__ void threefry2x32(uint32_t k0, uint32_t k1,
                                             uint32_t c0, uint32_t c1,
                                             uint32_t& o0, uint32_t& o1) {
  uint32_t ks2 = 0x1BD11BDAu ^ k0 ^ k1;
  uint32_t x0 = c0 + k0;
  uint32_t x1 = c1 + k1;
#define TFR(r) { x0 += x1; x1 = rotl32(x1, (r)); x1 ^= x0; }
  TFR(13) TFR(15) TFR(26) TFR(6)
  x0 += k1;  x1 += ks2 + 1u;
  TFR(17) TFR(29) TFR(16) TFR(24)
  x0 += ks2; x1 += k0 + 2u;
  TFR(13) TFR(15) TFR(26) TFR(6)
  x0 += k0;  x1 += k1 + 3u;
  TFR(17) TFR(29) TFR(16) TFR(24)
  x0 += k1;  x1 += ks2 + 4u;
  TFR(13) TFR(15) TFR(26) TFR(6)
  x0 += ks2; x1 += k0 + 5u;
#undef TFR
  o0 = x0; o1 = x1;
}

// VERIFIED round 3: partitionable threefry, bits = o0^o1, counter (0, j).
__global__ void hydrate_w_kernel(uint16_t* __restrict__ W,
                                 const int* __restrict__ seed_ptr) {
  uint32_t k1 = (uint32_t)(*seed_ptr);            // key = (0, seed)
  uint32_t j = blockIdx.x * 256u + threadIdx.x;   // 0 .. 2^24-1
  uint32_t o0, o1;
  threefry2x32(0u, k1, 0u, j, o0, o1);
  uint32_t bits = o0 ^ o1;
  const float scale = 0.03125f;
  const float mn    = -0.015625f;
  float f = __uint_as_float((bits >> 9) | 0x3F800000u) - 1.0f;
  float v = fmaxf(mn, f * scale + mn);
  W[j] = f2bf_rne(v);
}

__global__ void convert_x_kernel(const float* __restrict__ x,
                                 uint16_t* __restrict__ xb) {
  uint32_t base = (blockIdx.x * 256u + threadIdx.x) * 8u;
  f32x4 a = *(const f32x4*)(x + base);
  f32x4 b = *(const f32x4*)(x + base + 4);
  union { uint16_t u[8]; bf16x8 v; } r;
  r.u[0] = f2bf_rne(a[0]); r.u[1] = f2bf_rne(a[1]);
  r.u[2] = f2bf_rne(a[2]); r.u[3] = f2bf_rne(a[3]);
  r.u[4] = f2bf_rne(b[0]); r.u[5] = f2bf_rne(b[1]);
  r.u[6] = f2bf_rne(b[2]); r.u[7] = f2bf_rne(b[3]);
  *(bf16x8*)(xb + base) = r.v;
}

// ---------------------------------------------------------------------------
// 256x256 / BK=64 / 8-wave / 8-phase GEMM with counted vmcnt (T2+T3+T4+T5).
//
// LDS layout per buffer: A [256 rows][64 k] (32 KB) then B same.  Physical
// byte within a 128B row is XOR-swizzled: phys = logical ^ ((row&7)<<4).
// gload_lds keeps a LINEAR dest; the swizzle is applied by pre-swizzling the
// per-lane GLOBAL source column: src_kb = 16*((lane&7) ^ (lane>>3)).
//
// Wave bands (interleaved so quadrants release LDS halves early):
//   A rows: wm*64 + mh*128 + i*16 + fr        (wm = wid>>2)
//   B cols: wn*32 + nh*128 + j*16 + fr        (wn = wid&3)
// Quadrant order (mh,nh): (0,0),(0,1),(1,0),(1,1):
//   A-half0 free after P2, B-half0 after P3, A1/B1 after P4.
// Stage slots: P1: A1(kt+1), P2: B1(kt+1), P3: A0(kt+2), P4: B0(kt+2).
// vmcnt(6) per phase keeps 3 half-tiles in flight; min stage->first-read
// distance is 4 phases (B1), so every read is guarded. Single vmcnt(0)
// drain at tile 62 of 64 covers the tail.
// ---------------------------------------------------------------------------
__global__ __launch_bounds__(512, 2)
void gemm_bias_kernel(const uint16_t* __restrict__ A,   // x  bf16 [TOKENS][KIN]
                      const uint16_t* __restrict__ B,   // W  bf16 [NOUT][KIN]
                      const float* __restrict__ bias,
                      float* __restrict__ C) {
  __shared__ uint16_t smem[2][2][16384];   // [buf][A=0/B=1][32KB] = 128 KiB

  const int nwgn = NOUT / BN;                 // 16
  const int nwg  = (TOKENS / BM) * nwgn;      // 512 (divisible by 8)
  int bid = blockIdx.x;
  int cpx = nwg >> 3;
  int swzb = (bid & 7) * cpx + (bid >> 3);    // bijective XCD swizzle
  int tm = (swzb / nwgn) * BM;
  int tn = (swzb % nwgn) * BN;

  const int t    = threadIdx.x;
  const int lane = t & 63;
  const int wid  = t >> 6;       // 0..7
  const int wm   = wid >> 2;     // 0..1
  const int wn   = wid & 3;      // 0..3
  const int fr   = lane & 15;
  const int fq   = lane >> 4;

  const int swzRd = (lane & 7) << 4;                    // frag-read byte XOR
  const int lsw   = ((lane & 7) ^ (lane >> 3)) << 4;    // stage src byte offset

  f32x4 acc[8][4] = {};

  // Stage one half-tile (128 rows x 64 k) of matrix mat into buffer buf.
  // 2 x global_load_lds per wave; linear LDS dest, inverse-swizzled source.
  auto stageHalf = [&](int mat, int h, int kt, int buf) {
    const uint16_t* g = mat ? B : A;
    const int rb = (mat ? tn : tm) + h * 128 + wid * 16 + (lane >> 3);
    const char* src = (const char*)(g + (size_t)rb * KIN) + kt * 128 + lsw;
    char* dst = (char*)&smem[buf][mat][0] + h * 16384 + wid * 2048 + lane * 16;
#pragma unroll
    for (int q = 0; q < 2; ++q) {
      __builtin_amdgcn_global_load_lds(
          (const __attribute__((address_space(1))) void*)(src + (size_t)q * 8 * KIN * 2),
          (__attribute__((address_space(3))) void*)(dst + q * 1024),
          16, 0, 0);
    }
  };

#define PHASE(BUF, MH, NH, DO_STAGE, SMAT, SH, SKT, SBUF, WAITN)               \
  {                                                                            \
    bf16x8 af[2][4], bv[2][2];                                                 \
    const char* Ab = (const char*)&smem[BUF][0][0];                            \
    const char* Bb = (const char*)&smem[BUF][1][0];                            \
    _Pragma("unroll")                                                          \
    for (int s = 0; s < 2; ++s) {                                              \
      const int kb = (s << 6) | (fq << 4);                                     \
      _Pragma("unroll")                                                        \
      for (int i = 0; i < 4; ++i)                                              \
        af[s][i] = *(const bf16x8*)(Ab +                                       \
            (wm * 64 + (MH) * 128 + i * 16 + fr) * 128 + (kb ^ swzRd));        \
      _Pragma("unroll")                                                        \
      for (int j = 0; j < 2; ++j)                                              \
        bv[s][j] = *(const bf16x8*)(Bb +                                       \
            (wn * 32 + (NH) * 128 + j * 16 + fr) * 128 + (kb ^ swzRd));        \
    }                                                                          \
    if (DO_STAGE) stageHalf(SMAT, SH, SKT, SBUF);                              \
    asm volatile("s_waitcnt vmcnt(" #WAITN ")" ::: "memory");                  \
    __builtin_amdgcn_s_barrier();                                              \
    asm volatile("s_waitcnt lgkmcnt(0)" ::: "memory");                         \
    __builtin_amdgcn_sched_barrier(0);                                         \
    __builtin_amdgcn_s_setprio(1);                                             \
    _Pragma("unroll")                                                          \
    for (int s = 0; s < 2; ++s)                                                \
      _Pragma("unroll")                                                        \
      for (int i = 0; i < 4; ++i)                                              \
        _Pragma("unroll")                                                      \
        for (int j = 0; j < 2; ++j)                                            \
          acc[(MH) * 4 + i][(NH) * 2 + j] =                                    \
              __builtin_amdgcn_mfma_f32_16x16x32_bf16(                         \
                  af[s][i], bv[s][j], acc[(MH) * 4 + i][(NH) * 2 + j], 0, 0, 0); \
    __builtin_amdgcn_s_setprio(0);                                             \
    __builtin_amdgcn_s_barrier();                                              \
  }

  // Prologue: kt0 fully (A0,B0,A1,B1) + kt1's A0,B0; force kt0 landed.
  stageHalf(0, 0, 0, 0); stageHalf(1, 0, 0, 0);
  stageHalf(0, 1, 0, 0); stageHalf(1, 1, 0, 0);
  stageHalf(0, 0, 1, 1); stageHalf(1, 0, 1, 1);
  asm volatile("s_waitcnt vmcnt(4)" ::: "memory");
  __builtin_amdgcn_s_barrier();

  // Main loop: tiles 0..61, two per iteration (literal buffers).
  for (int kt = 0; kt < NT - 2; kt += 2) {
    // even tile kt -> buf0; stages: A1/B1 of kt+1 (buf1), A0/B0 of kt+2 (buf0)
    PHASE(0, 0, 0, 1, 0, 1, kt + 1, 1, 6)
    PHASE(0, 0, 1, 1, 1, 1, kt + 1, 1, 6)
    PHASE(0, 1, 0, 1, 0, 0, kt + 2, 0, 6)
    PHASE(0, 1, 1, 1, 1, 0, kt + 2, 0, 6)
    // odd tile kt+1 -> buf1; stages: A1/B1 of kt+2 (buf0), A0/B0 of kt+3 (buf1)
    PHASE(1, 0, 0, 1, 0, 1, kt + 2, 0, 6)
    PHASE(1, 0, 1, 1, 1, 1, kt + 2, 0, 6)
    PHASE(1, 1, 0, 1, 0, 0, kt + 3, 1, 6)
    PHASE(1, 1, 1, 1, 1, 0, kt + 3, 1, 6)
  }

  // kt = 62 (buf0): stage only A1/B1 of 63; drain at P4.
  PHASE(0, 0, 0, 1, 0, 1, 63, 1, 6)
  PHASE(0, 0, 1, 1, 1, 1, 63, 1, 6)
  PHASE(0, 1, 0, 0, 0, 0, 0, 0, 6)
  PHASE(0, 1, 1, 0, 0, 0, 0, 0, 0)
  // kt = 63 (buf1): no stages, everything landed.
  PHASE(1, 0, 0, 0, 0, 0, 0, 0, 0)
  PHASE(1, 0, 1, 0, 0, 0, 0, 0, 0)
  PHASE(1, 1, 0, 0, 0, 0, 0, 0, 0)
  PHASE(1, 1, 1, 0, 0, 0, 0, 0, 0)
#undef PHASE

  // Epilogue: D row = fq*4 + rr, col = fr (m89/m91-verified), fused bias.
#pragma unroll
  for (int nj = 0; nj < 4; ++nj) {
    const int nh = nj >> 1, j = nj & 1;
    const int col = tn + wn * 32 + nh * 128 + j * 16 + fr;
    const float bvs = bias[col];
#pragma unroll
    for (int mi = 0; mi < 8; ++mi) {
      const int mh = mi >> 2, i = mi & 3;
      const int row0 = tm + wm * 64 + mh * 128 + i * 16 + fq * 4;
#pragma unroll
      for (int rr = 0; rr < 4; ++rr)
        C[(size_t)(row0 + rr) * NOUT + col] = acc[mi][nj][rr] + bvs;
    }
  }
}

extern "C" void kernel_launch(void* const* d_in, const int* in_sizes, int n_in,
                              void* d_out, int out_size, void* d_ws, size_t ws_size,
                              hipStream_t stream) {
  const float* x    = (const float*)d_in[0];   // [8192][4096] fp32
  const float* bias = (const float*)d_in[1];   // [4096] fp32
  const int*   seed = (const int*)d_in[2];     // [1] int
  float* y = (float*)d_out;                    // [8192][4096] fp32

  // workspace: W bf16 (32 MB) | x bf16 (64 MB) — 96 MB, proven available
  uint16_t* Wb = (uint16_t*)d_ws;
  uint16_t* Xb = Wb + (size_t)NOUT * KIN;

  hydrate_w_kernel<<<(1u << 24) / 256, 256, 0, stream>>>(Wb, seed);
  convert_x_kernel<<<(TOKENS * KIN / 8) / 256, 256, 0, stream>>>(x, Xb);

  const int grid = (TOKENS / BM) * (NOUT / BN);   // 512
  gemm_bias_kernel<<<grid, 512, 0, stream>>>(Xb, Wb, bias, y);
}

// Round 6
// 284.318 us; speedup vs baseline: 1.8309x; 1.1090x over previous
//
#include <hip/hip_runtime.h>
#include <hip/hip_bf16.h>
#include <stdint.h>

#define TOKENS 8192
#define NOUT   4096
#define KIN    4096

#define BM 256
#define BN 256
#define BK 64
#define NT (KIN / BK)   // 64 K-tiles

typedef __attribute__((ext_vector_type(8))) short bf16x8;
typedef __attribute__((ext_vector_type(4))) float f32x4;

__device__ __forceinline__ uint32_t rotl32(uint32_t x, int r) {
  return (x << r) | (x >> (32 - r));
}

__device__ __forceinline__ uint16_t f2bf_rne(float f) {
  uint32_t u = __float_as_uint(f);
  u += 0x7FFFu + ((u >> 16) & 1u);
  return (uint16_t)(u >> 16);
}

// Threefry-2x32, 20 rounds — JAX PRNG core.
__device__ __forceinline__ void threefry2x32(uint32_t k0, uint32_t k1,
                                             uint32_t c0, uint32_t c1,
                                             uint32_t& o0, uint32_t& o1) {
  uint32_t ks2 = 0x1BD11BDAu ^ k0 ^ k1;
  uint32_t x0 = c0 + k0;
  uint32_t x1 = c1 + k1;
#define TFR(r) { x0 += x1; x1 = rotl32(x1, (r)); x1 ^= x0; }
  TFR(13) TFR(15) TFR(26) TFR(6)
  x0 += k1;  x1 += ks2 + 1u;
  TFR(17) TFR(29) TFR(16) TFR(24)
  x0 += ks2; x1 += k0 + 2u;
  TFR(13) TFR(15) TFR(26) TFR(6)
  x0 += k0;  x1 += k1 + 3u;
  TFR(17) TFR(29) TFR(16) TFR(24)
  x0 += k1;  x1 += ks2 + 4u;
  TFR(13) TFR(15) TFR(26) TFR(6)
  x0 += ks2; x1 += k0 + 5u;
#undef TFR
  o0 = x0; o1 = x1;
}

// Fused prep: blocks [0, 65536) hydrate W (1 elem/thread, partitionable
// threefry — VERIFIED round 3); blocks [65536, 81920) convert x fp32->bf16
// (8 elems/thread). VALU-bound hydrate overlaps BW-bound convert.
__global__ void prep_kernel(const float* __restrict__ x,
                            uint16_t* __restrict__ xb,
                            uint16_t* __restrict__ W,
                            const int* __restrict__ seed_ptr) {
  uint32_t b = blockIdx.x;
  if (b < 65536u) {
    uint32_t k1 = (uint32_t)(*seed_ptr);            // key = (0, seed)
    uint32_t j = b * 256u + threadIdx.x;            // 0 .. 2^24-1
    uint32_t o0, o1;
    threefry2x32(0u, k1, 0u, j, o0, o1);
    uint32_t bits = o0 ^ o1;
    const float scale = 0.03125f;
    const float mn    = -0.015625f;
    float f = __uint_as_float((bits >> 9) | 0x3F800000u) - 1.0f;
    float v = fmaxf(mn, f * scale + mn);
    W[j] = f2bf_rne(v);
  } else {
    uint32_t base = ((b - 65536u) * 256u + threadIdx.x) * 8u;
    f32x4 a = *(const f32x4*)(x + base);
    f32x4 c = *(const f32x4*)(x + base + 4);
    union { uint16_t u[8]; bf16x8 v; } r;
    r.u[0] = f2bf_rne(a[0]); r.u[1] = f2bf_rne(a[1]);
    r.u[2] = f2bf_rne(a[2]); r.u[3] = f2bf_rne(a[3]);
    r.u[4] = f2bf_rne(c[0]); r.u[5] = f2bf_rne(c[1]);
    r.u[6] = f2bf_rne(c[2]); r.u[7] = f2bf_rne(c[3]);
    *(bf16x8*)(xb + base) = r.v;
  }
}

// ---------------------------------------------------------------------------
// 256x256 / BK=64 / 8-wave / 8-phase GEMM (T2+T3+T4+T5) with cross-phase
// operand register caching (24 ds_read_b128 per K-tile/wave, not 48).
//
// Quadrant order (mh,nh): (0,0),(0,1),(1,1),(1,0):
//   P1: read A0+B0 -> MFMA(0,0)   [stage A1(kt+1) -> buf^1]
//   P2: read B1    -> MFMA(0,1)   [stage B1(kt+1) -> buf^1]
//   P3: read A1    -> MFMA(1,1)   [stage A0(kt+2) -> buf  ]
//   P4: no reads   -> MFMA(1,0)   [stage B0(kt+2) -> buf  ]
// Last-read: A0,B0 @P1; B1 @P2; A1 @P3 — every stage overwrites strictly
// after the region's last read. vmcnt(6) = 3 half-tiles in flight; staged
// loads land >=1 phase before first read (min distance 4 phases), and the
// p+3-wait + barrier chain guarantees cross-wave visibility (validated r5).
// LDS swizzle: linear gload_lds dest + inverse-swizzled global source
// (lsw), reads XOR byte ((row&7)<<4). Round 5 measured 0 bank conflicts.
// ---------------------------------------------------------------------------
__global__ __launch_bounds__(512, 2)
void gemm_bias_kernel(const uint16_t* __restrict__ A,   // x  bf16 [TOKENS][KIN]
                      const uint16_t* __restrict__ B,   // W  bf16 [NOUT][KIN]
                      const float* __restrict__ bias,
                      float* __restrict__ C) {
  __shared__ uint16_t smem[2][2][16384];   // [buf][A=0/B=1][32KB] = 128 KiB

  const int nwgn = NOUT / BN;                 // 16
  const int nwg  = (TOKENS / BM) * nwgn;      // 512 (divisible by 8)
  int bid = blockIdx.x;
  int cpx = nwg >> 3;
  int swzb = (bid & 7) * cpx + (bid >> 3);    // bijective XCD swizzle
  int tm = (swzb / nwgn) * BM;
  int tn = (swzb % nwgn) * BN;

  const int t    = threadIdx.x;
  const int lane = t & 63;
  const int wid  = t >> 6;       // 0..7
  const int wm   = wid >> 2;     // 0..1
  const int wn   = wid & 3;      // 0..3
  const int fr   = lane & 15;
  const int fq   = lane >> 4;

  const int swzRd = (lane & 7) << 4;                    // frag-read byte XOR
  const int lsw   = ((lane & 7) ^ (lane >> 3)) << 4;    // stage src byte offset

  f32x4 acc[8][4] = {};

  auto stageHalf = [&](int mat, int h, int kt, int buf) {
    const uint16_t* g = mat ? B : A;
    const int rb = (mat ? tn : tm) + h * 128 + wid * 16 + (lane >> 3);
    const char* src = (const char*)(g + (size_t)rb * KIN) + kt * 128 + lsw;
    char* dst = (char*)&smem[buf][mat][0] + h * 16384 + wid * 2048 + lane * 16;
#pragma unroll
    for (int q = 0; q < 2; ++q) {
      __builtin_amdgcn_global_load_lds(
          (const __attribute__((address_space(1))) void*)(src + (size_t)q * 8 * KIN * 2),
          (__attribute__((address_space(3))) void*)(dst + q * 1024),
          16, 0, 0);
    }
  };

#define VMW(N) asm volatile("s_waitcnt vmcnt(" #N ")" ::: "memory")

#define RD_A(Ab, MH)                                                           \
    _Pragma("unroll")                                                          \
    for (int s = 0; s < 2; ++s) {                                              \
      const int kb = (s << 6) | (fq << 4);                                     \
      _Pragma("unroll")                                                        \
      for (int i = 0; i < 4; ++i)                                              \
        af[s][i] = *(const bf16x8*)((Ab) +                                     \
            (wm * 64 + (MH) * 128 + i * 16 + fr) * 128 + (kb ^ swzRd));        \
    }

#define RD_B(Bb, BV, NH)                                                       \
    _Pragma("unroll")                                                          \
    for (int s = 0; s < 2; ++s) {                                              \
      const int kb = (s << 6) | (fq << 4);                                     \
      _Pragma("unroll")                                                        \
      for (int j = 0; j < 2; ++j)                                              \
        BV[s][j] = *(const bf16x8*)((Bb) +                                     \
            (wn * 32 + (NH) * 128 + j * 16 + fr) * 128 + (kb ^ swzRd));        \
    }

#define MFCL(MH, NH, BV)                                                       \
    __builtin_amdgcn_s_barrier();                                              \
    asm volatile("s_waitcnt lgkmcnt(0)" ::: "memory");                         \
    __builtin_amdgcn_sched_barrier(0);                                         \
    __builtin_amdgcn_s_setprio(1);                                             \
    _Pragma("unroll")                                                          \
    for (int s = 0; s < 2; ++s)                                                \
      _Pragma("unroll")                                                        \
      for (int i = 0; i < 4; ++i)                                              \
        _Pragma("unroll")                                                      \
        for (int j = 0; j < 2; ++j)                                            \
          acc[(MH) * 4 + i][(NH) * 2 + j] =                                    \
              __builtin_amdgcn_mfma_f32_16x16x32_bf16(                         \
                  af[s][i], BV[s][j], acc[(MH) * 4 + i][(NH) * 2 + j], 0, 0, 0); \
    __builtin_amdgcn_s_setprio(0);                                             \
    __builtin_amdgcn_s_barrier();

  // MODE: 0 = main loop (full stages, all vmcnt(6))
  //       1 = tile 62  (stage P1,P2 only; P4 drains vmcnt(0))
  //       2 = tile 63  (no stages, vmcnt(0))
#define KTILE(BUF, KT, MODE)                                                   \
  {                                                                            \
    bf16x8 af[2][4], bv0[2][2], bv1[2][2];                                     \
    const char* Ab = (const char*)&smem[BUF][0][0];                            \
    const char* Bb = (const char*)&smem[BUF][1][0];                            \
    /* P1 */                                                                   \
    RD_A(Ab, 0) RD_B(Bb, bv0, 0)                                               \
    if ((MODE) <= 1) stageHalf(0, 1, (KT) + 1, (BUF) ^ 1);                     \
    if ((MODE) <= 1) { VMW(6); } else { VMW(0); }                              \
    MFCL(0, 0, bv0)                                                            \
    /* P2 */                                                                   \
    RD_B(Bb, bv1, 1)                                                           \
    if ((MODE) <= 1) stageHalf(1, 1, (KT) + 1, (BUF) ^ 1);                     \
    if ((MODE) <= 1) { VMW(6); } else { VMW(0); }                              \
    MFCL(0, 1, bv1)                                                            \
    /* P3 */                                                                   \
    RD_A(Ab, 1)                                                                \
    if ((MODE) == 0) stageHalf(0, 0, (KT) + 2, (BUF));                         \
    if ((MODE) <= 1) { VMW(6); } else { VMW(0); }                              \
    MFCL(1, 1, bv1)                                                            \
    /* P4 */                                                                   \
    if ((MODE) == 0) stageHalf(1, 0, (KT) + 2, (BUF));                         \
    if ((MODE) == 0) { VMW(6); } else { VMW(0); }                              \
    MFCL(1, 0, bv0)                                                            \
  }

  // Prologue: kt0 fully (A0,B0,A1,B1)->buf0 + kt1's A0,B0->buf1; land kt0.
  stageHalf(0, 0, 0, 0); stageHalf(1, 0, 0, 0);
  stageHalf(0, 1, 0, 0); stageHalf(1, 1, 0, 0);
  stageHalf(0, 0, 1, 1); stageHalf(1, 0, 1, 1);
  VMW(4);
  __builtin_amdgcn_s_barrier();

  for (int kt = 0; kt < NT - 2; kt += 2) {
    KTILE(0, kt, 0)
    KTILE(1, kt + 1, 0)
  }
  KTILE(0, 62, 1)
  KTILE(1, 63, 2)

#undef KTILE
#undef MFCL
#undef RD_B
#undef RD_A
#undef VMW

  // Epilogue: D row = fq*4 + rr, col = fr (m89/m91-verified), fused bias.
#pragma unroll
  for (int nj = 0; nj < 4; ++nj) {
    const int nh = nj >> 1, j = nj & 1;
    const int col = tn + wn * 32 + nh * 128 + j * 16 + fr;
    const float bvs = bias[col];
#pragma unroll
    for (int mi = 0; mi < 8; ++mi) {
      const int mh = mi >> 2, i = mi & 3;
      const int row0 = tm + wm * 64 + mh * 128 + i * 16 + fq * 4;
#pragma unroll
      for (int rr = 0; rr < 4; ++rr)
        C[(size_t)(row0 + rr) * NOUT + col] = acc[mi][nj][rr] + bvs;
    }
  }
}

extern "C" void kernel_launch(void* const* d_in, const int* in_sizes, int n_in,
                              void* d_out, int out_size, void* d_ws, size_t ws_size,
                              hipStream_t stream) {
  const float* x    = (const float*)d_in[0];   // [8192][4096] fp32
  const float* bias = (const float*)d_in[1];   // [4096] fp32
  const int*   seed = (const int*)d_in[2];     // [1] int
  float* y = (float*)d_out;                    // [8192][4096] fp32

  // workspace: W bf16 (32 MB) | x bf16 (64 MB) — 96 MB, proven available
  uint16_t* Wb = (uint16_t*)d_ws;
  uint16_t* Xb = Wb + (size_t)NOUT * KIN;

  // fused hydrate (65536 blocks) + convert (16384 blocks)
  prep_kernel<<<65536 + 16384, 256, 0, stream>>>(x, Xb, Wb, seed);

  const int grid = (TOKENS / BM) * (NOUT / BN);   // 512
  gemm_bias_kernel<<<grid, 512, 0, stream>>>(Xb, Wb, bias, y);
}

// Round 7
// 284.108 us; speedup vs baseline: 1.8322x; 1.0007x over previous
//
#include <hip/hip_runtime.h>
#include <hip/hip_bf16.h>
#include <stdint.h>

#define TOKENS 8192
#define NOUT   4096
#define KIN    4096

#define BM 256
#define BN 256
#define BK 64
#define NT (KIN / BK)   // 64 K-tiles

typedef __attribute__((ext_vector_type(8))) short bf16x8;
typedef __attribute__((ext_vector_type(4))) float f32x4;

__device__ __forceinline__ uint32_t rotl32(uint32_t x, int r) {
  return (x << r) | (x >> (32 - r));
}

__device__ __forceinline__ uint16_t f2bf_rne(float f) {
  uint32_t u = __float_as_uint(f);
  u += 0x7FFFu + ((u >> 16) & 1u);
  return (uint16_t)(u >> 16);
}

// Threefry-2x32, 20 rounds — JAX PRNG core.
__device__ __forceinline__ void threefry2x32(uint32_t k0, uint32_t k1,
                                             uint32_t c0, uint32_t c1,
                                             uint32_t& o0, uint32_t& o1) {
  uint32_t ks2 = 0x1BD11BDAu ^ k0 ^ k1;
  uint32_t x0 = c0 + k0;
  uint32_t x1 = c1 + k1;
#define TFR(r) { x0 += x1; x1 = rotl32(x1, (r)); x1 ^= x0; }
  TFR(13) TFR(15) TFR(26) TFR(6)
  x0 += k1;  x1 += ks2 + 1u;
  TFR(17) TFR(29) TFR(16) TFR(24)
  x0 += ks2; x1 += k0 + 2u;
  TFR(13) TFR(15) TFR(26) TFR(6)
  x0 += k0;  x1 += k1 + 3u;
  TFR(17) TFR(29) TFR(16) TFR(24)
  x0 += k1;  x1 += ks2 + 4u;
  TFR(13) TFR(15) TFR(26) TFR(6)
  x0 += ks2; x1 += k0 + 5u;
#undef TFR
  o0 = x0; o1 = x1;
}

// Fused prep: blocks [0, 65536) hydrate W (partitionable threefry —
// VERIFIED round 3); blocks [65536, 81920) convert x fp32->bf16.
__global__ void prep_kernel(const float* __restrict__ x,
                            uint16_t* __restrict__ xb,
                            uint16_t* __restrict__ W,
                            const int* __restrict__ seed_ptr) {
  uint32_t b = blockIdx.x;
  if (b < 65536u) {
    uint32_t k1 = (uint32_t)(*seed_ptr);            // key = (0, seed)
    uint32_t j = b * 256u + threadIdx.x;            // 0 .. 2^24-1
    uint32_t o0, o1;
    threefry2x32(0u, k1, 0u, j, o0, o1);
    uint32_t bits = o0 ^ o1;
    const float scale = 0.03125f;
    const float mn    = -0.015625f;
    float f = __uint_as_float((bits >> 9) | 0x3F800000u) - 1.0f;
    float v = fmaxf(mn, f * scale + mn);
    W[j] = f2bf_rne(v);
  } else {
    uint32_t base = ((b - 65536u) * 256u + threadIdx.x) * 8u;
    f32x4 a = *(const f32x4*)(x + base);
    f32x4 c = *(const f32x4*)(x + base + 4);
    union { uint16_t u[8]; bf16x8 v; } r;
    r.u[0] = f2bf_rne(a[0]); r.u[1] = f2bf_rne(a[1]);
    r.u[2] = f2bf_rne(a[2]); r.u[3] = f2bf_rne(a[3]);
    r.u[4] = f2bf_rne(c[0]); r.u[5] = f2bf_rne(c[1]);
    r.u[6] = f2bf_rne(c[2]); r.u[7] = f2bf_rne(c[3]);
    *(bf16x8*)(xb + base) = r.v;
  }
}

// ---------------------------------------------------------------------------
// 256x256 / BK=64 / 8-wave / 8-phase GEMM (T2+T3+T4+T5), operand reg-caching,
// SINGLE vmcnt(6) per K-tile at P4 (m201 template discipline).
//
// Quadrant order (mh,nh): (0,0),(0,1),(1,1),(1,0); reads 12/4/8/0.
// Stage slots (re-derived for single-wait RAW/WAR):
//   P1: A1(kt+1) -> buf^1      [A1 last read P3 of prev cycle]
//   P2: A0(kt+2) -> buf        [A0 last read P1 this tile]
//   P3: B0(kt+2) -> buf        [B0 last read P1 this tile]
//   P4: B1(kt+2) -> buf        [B1 last read P2 this tile] + vmcnt(6)
// RAW: at P4's vmcnt(6), the 6 newest loads are P2/P3/P4's (kt+2) stages,
// so A1(kt+1) and everything older has landed -> kt+1 fully resident
// before its first ds_read. WAR: every stage lands >= 1 barrier-pair after
// the region's last read (reads complete at lgkmcnt(0) before the trailing
// barrier). Prologue: 4 halves -> vmcnt(4), +3 halves -> vmcnt(6) (template).
// Tail: kt62 stages only A1(63), drains vmcnt(0) at its P4; kt63 waitless.
// lgkmcnt(8) pre-drain on the 12-read phase (P1) per template.
// LDS swizzle: linear gload_lds dest + inverse-swizzled global source;
// reads XOR byte ((row&7)<<4). Rounds 5/6 measured 0 bank conflicts.
// ---------------------------------------------------------------------------
__global__ __launch_bounds__(512, 2)
void gemm_bias_kernel(const uint16_t* __restrict__ A,   // x  bf16 [TOKENS][KIN]
                      const uint16_t* __restrict__ B,   // W  bf16 [NOUT][KIN]
                      const float* __restrict__ bias,
                      float* __restrict__ C) {
  __shared__ uint16_t smem[2][2][16384];   // [buf][A=0/B=1][32KB] = 128 KiB

  const int nwgn = NOUT / BN;                 // 16
  const int nwg  = (TOKENS / BM) * nwgn;      // 512 (divisible by 8)
  int bid = blockIdx.x;
  int cpx = nwg >> 3;
  int swzb = (bid & 7) * cpx + (bid >> 3);    // bijective XCD swizzle
  int tm = (swzb / nwgn) * BM;
  int tn = (swzb % nwgn) * BN;

  const int t    = threadIdx.x;
  const int lane = t & 63;
  const int wid  = t >> 6;       // 0..7
  const int wm   = wid >> 2;     // 0..1
  const int wn   = wid & 3;      // 0..3
  const int fr   = lane & 15;
  const int fq   = lane >> 4;

  const int swzRd = (lane & 7) << 4;                    // frag-read byte XOR
  const int lsw   = ((lane & 7) ^ (lane >> 3)) << 4;    // stage src byte offset

  f32x4 acc[8][4] = {};

  auto stageHalf = [&](int mat, int h, int kt, int buf) {
    const uint16_t* g = mat ? B : A;
    const int rb = (mat ? tn : tm) + h * 128 + wid * 16 + (lane >> 3);
    const char* src = (const char*)(g + (size_t)rb * KIN) + kt * 128 + lsw;
    char* dst = (char*)&smem[buf][mat][0] + h * 16384 + wid * 2048 + lane * 16;
#pragma unroll
    for (int q = 0; q < 2; ++q) {
      __builtin_amdgcn_global_load_lds(
          (const __attribute__((address_space(1))) void*)(src + (size_t)q * 8 * KIN * 2),
          (__attribute__((address_space(3))) void*)(dst + q * 1024),
          16, 0, 0);
    }
  };

#define VMW(N) asm volatile("s_waitcnt vmcnt(" #N ")" ::: "memory")
#define LKW(N) asm volatile("s_waitcnt lgkmcnt(" #N ")" ::: "memory")

#define RD_A(Ab, MH)                                                           \
    _Pragma("unroll")                                                          \
    for (int s = 0; s < 2; ++s) {                                              \
      const int kb = (s << 6) | (fq << 4);                                     \
      _Pragma("unroll")                                                        \
      for (int i = 0; i < 4; ++i)                                              \
        af[s][i] = *(const bf16x8*)((Ab) +                                     \
            (wm * 64 + (MH) * 128 + i * 16 + fr) * 128 + (kb ^ swzRd));        \
    }

#define RD_B(Bb, BV, NH)                                                       \
    _Pragma("unroll")                                                          \
    for (int s = 0; s < 2; ++s) {                                              \
      const int kb = (s << 6) | (fq << 4);                                     \
      _Pragma("unroll")                                                        \
      for (int j = 0; j < 2; ++j)                                              \
        BV[s][j] = *(const bf16x8*)((Bb) +                                     \
            (wn * 32 + (NH) * 128 + j * 16 + fr) * 128 + (kb ^ swzRd));        \
    }

#define MFCL(MH, NH, BV)                                                       \
    __builtin_amdgcn_s_barrier();                                              \
    asm volatile("s_waitcnt lgkmcnt(0)" ::: "memory");                         \
    __builtin_amdgcn_sched_barrier(0);                                         \
    __builtin_amdgcn_s_setprio(1);                                             \
    _Pragma("unroll")                                                          \
    for (int s = 0; s < 2; ++s)                                                \
      _Pragma("unroll")                                                        \
      for (int i = 0; i < 4; ++i)                                              \
        _Pragma("unroll")                                                      \
        for (int j = 0; j < 2; ++j)                                            \
          acc[(MH) * 4 + i][(NH) * 2 + j] =                                    \
              __builtin_amdgcn_mfma_f32_16x16x32_bf16(                         \
                  af[s][i], BV[s][j], acc[(MH) * 4 + i][(NH) * 2 + j], 0, 0, 0); \
    __builtin_amdgcn_s_setprio(0);                                             \
    __builtin_amdgcn_s_barrier();

  // MODE: 0 = main loop; 1 = kt 62 (stage A1(63) only, drain vmcnt(0) at P4);
  //       2 = kt 63 (no stages, no vm waits).
#define KTILE(BUF, KT, MODE)                                                   \
  {                                                                            \
    bf16x8 af[2][4], bv0[2][2], bv1[2][2];                                     \
    const char* Ab = (const char*)&smem[BUF][0][0];                            \
    const char* Bb = (const char*)&smem[BUF][1][0];                            \
    /* P1: reads A0+B0 (12); stage A1(kt+1)->buf^1 */                          \
    RD_A(Ab, 0) RD_B(Bb, bv0, 0)                                               \
    if ((MODE) <= 1) stageHalf(0, 1, (KT) + 1, (BUF) ^ 1);                     \
    LKW(8);                                                                    \
    MFCL(0, 0, bv0)                                                            \
    /* P2: reads B1 (4); stage A0(kt+2)->buf */                                \
    RD_B(Bb, bv1, 1)                                                           \
    if ((MODE) == 0) stageHalf(0, 0, (KT) + 2, (BUF));                         \
    MFCL(0, 1, bv1)                                                            \
    /* P3: reads A1 (8); stage B0(kt+2)->buf */                                \
    RD_A(Ab, 1)                                                                \
    if ((MODE) == 0) stageHalf(1, 0, (KT) + 2, (BUF));                         \
    MFCL(1, 1, bv1)                                                            \
    /* P4: no reads; stage B1(kt+2)->buf; the ONE vm wait per K-tile */        \
    if ((MODE) == 0) stageHalf(1, 1, (KT) + 2, (BUF));                         \
    if ((MODE) == 0) { VMW(6); } else if ((MODE) == 1) { VMW(0); }             \
    MFCL(1, 0, bv0)                                                            \
  }

  // Prologue (template: vmcnt(4) after 4 halves, vmcnt(6) after +3):
  stageHalf(0, 0, 0, 0); stageHalf(1, 0, 0, 0);
  stageHalf(0, 1, 0, 0); stageHalf(1, 1, 0, 0);
  VMW(4);
  stageHalf(0, 0, 1, 1); stageHalf(1, 0, 1, 1); stageHalf(1, 1, 1, 1);
  VMW(6);
  __builtin_amdgcn_s_barrier();

  for (int kt = 0; kt < NT - 2; kt += 2) {
    KTILE(0, kt, 0)
    KTILE(1, kt + 1, 0)
  }
  KTILE(0, 62, 1)
  KTILE(1, 63, 2)

#undef KTILE
#undef MFCL
#undef RD_B
#undef RD_A
#undef LKW
#undef VMW

  // Epilogue: D row = fq*4 + rr, col = fr (m89/m91-verified), fused bias.
#pragma unroll
  for (int nj = 0; nj < 4; ++nj) {
    const int nh = nj >> 1, j = nj & 1;
    const int col = tn + wn * 32 + nh * 128 + j * 16 + fr;
    const float bvs = bias[col];
#pragma unroll
    for (int mi = 0; mi < 8; ++mi) {
      const int mh = mi >> 2, i = mi & 3;
      const int row0 = tm + wm * 64 + mh * 128 + i * 16 + fq * 4;
#pragma unroll
      for (int rr = 0; rr < 4; ++rr)
        C[(size_t)(row0 + rr) * NOUT + col] = acc[mi][nj][rr] + bvs;
    }
  }
}

extern "C" void kernel_launch(void* const* d_in, const int* in_sizes, int n_in,
                              void* d_out, int out_size, void* d_ws, size_t ws_size,
                              hipStream_t stream) {
  const float* x    = (const float*)d_in[0];   // [8192][4096] fp32
  const float* bias = (const float*)d_in[1];   // [4096] fp32
  const int*   seed = (const int*)d_in[2];     // [1] int
  float* y = (float*)d_out;                    // [8192][4096] fp32

  // workspace: W bf16 (32 MB) | x bf16 (64 MB) — 96 MB, proven available
  uint16_t* Wb = (uint16_t*)d_ws;
  uint16_t* Xb = Wb + (size_t)NOUT * KIN;

  prep_kernel<<<65536 + 16384, 256, 0, stream>>>(x, Xb, Wb, seed);

  const int grid = (TOKENS / BM) * (NOUT / BN);   // 512
  gemm_bias_kernel<<<grid, 512, 0, stream>>>(Xb, Wb, bias, y);
}